// Round 2
// baseline (365.603 us; speedup 1.0000x reference)
//
#include <hip/hip_runtime.h>
#include <hip/hip_bf16.h>

// DirectEncodingModel: B=16384, IN=512; 3 hidden group-layers (G=64,F=24,O=16)
// gather-from-growing-acc + tanh, then head (GO_G=4,GO_F=48,GO_O=16).
// acc cols per row: [0,512)=x, [512,1536)=L1, [1536,2560)=L2, [2560,3584)=L3.
// ALL float tensors are fp32 (reference is jnp.float32; round-1 NaN proved the
// bf16-input theory wrong). acc is stored in LDS as bf16 (57 KB) purely as a
// capacity/bandwidth optimization; all math is fp32.

typedef unsigned short ushort_t;
typedef unsigned int uint_t;

#define ROWS_PER_BLOCK 8
#define BLOCK_THREADS 256
#define ACC_COLS 3584

__device__ __forceinline__ float bf2f(ushort_t u) {
    union { uint_t i; float f; } v;
    v.i = ((uint_t)u) << 16;
    return v.f;
}

__device__ __forceinline__ ushort_t f2bf(float f) {
    union { float f; uint_t i; } v;
    v.f = f;
    uint_t x = v.i;
    uint_t r = (x + 0x7fffu + ((x >> 16) & 1u)) >> 16;  // RNE; inputs finite
    return (ushort_t)r;
}

__device__ __forceinline__ uint_t pack2bf(float lo, float hi) {
    return (uint_t)f2bf(lo) | ((uint_t)f2bf(hi) << 16);
}

__device__ __forceinline__ float fast_tanh(float x) {
    float cx = fminf(fmaxf(x, -9.0f), 9.0f);
    float e = __expf(2.0f * cx);
    return (e - 1.0f) * __builtin_amdgcn_rcpf(e + 1.0f);
}

__global__ __launch_bounds__(BLOCK_THREADS, 2)
void demodel_kernel(const float* __restrict__ x,
                    const float* __restrict__ W1, const float* __restrict__ b1,
                    const float* __restrict__ W2, const float* __restrict__ b2,
                    const float* __restrict__ W3, const float* __restrict__ b3,
                    const float* __restrict__ Wo, const float* __restrict__ bo,
                    const int* __restrict__ idx1, const int* __restrict__ idx2,
                    const int* __restrict__ idx3, const int* __restrict__ idxo,
                    float* __restrict__ out)
{
    // 8 rows x 3584 cols, bf16: 57344 bytes
    __shared__ __align__(16) ushort_t acc[ROWS_PER_BLOCK][ACC_COLS];

    const int t = threadIdx.x;
    const int row0 = blockIdx.x * ROWS_PER_BLOCK;

    // ---- Phase 0: stage x tile (8 rows x 512 fp32) into LDS as bf16 ----
    {
        const int r = t >> 5;          // 0..7
        const int c = (t & 31) << 4;   // 0..496, 16 floats per thread
        const float4* src = reinterpret_cast<const float4*>(x + (size_t)(row0 + r) * 512 + c);
        float4 v0 = src[0];
        float4 v1 = src[1];
        float4 v2 = src[2];
        float4 v3 = src[3];
        uint4 p0, p1;
        p0.x = pack2bf(v0.x, v0.y); p0.y = pack2bf(v0.z, v0.w);
        p0.z = pack2bf(v1.x, v1.y); p0.w = pack2bf(v1.z, v1.w);
        p1.x = pack2bf(v2.x, v2.y); p1.y = pack2bf(v2.z, v2.w);
        p1.z = pack2bf(v3.x, v3.y); p1.w = pack2bf(v3.z, v3.w);
        uint4* dst = reinterpret_cast<uint4*>(&acc[r][c]);
        dst[0] = p0;
        dst[1] = p1;
    }
    __syncthreads();

    // ---- Hidden layers: thread owns (group g, rows {s, s+4}) ----
    const int g = t & 63;   // 0..63
    const int s = t >> 6;   // 0..3
    const int r0 = s;
    const int r1 = s + 4;

    const float* Wl[3] = { W1, W2, W3 };
    const float* bl[3] = { b1, b2, b3 };
    const int* il[3] = { idx1, idx2, idx3 };

    int out_base = 512;
    #pragma unroll
    for (int l = 0; l < 3; ++l) {
        const int* idx = il[l] + g * 24;
        const float* W = Wl[l] + g * 384;   // g*24*16
        const float* bb = bl[l] + g * 16;

        float acc0[16], acc1[16];
        #pragma unroll
        for (int o = 0; o < 16; ++o) {
            float bv = bb[o];
            acc0[o] = bv;
            acc1[o] = bv;
        }

        for (int f = 0; f < 24; ++f) {
            const int ix = idx[f];
            const float a0 = bf2f(acc[r0][ix]);
            const float a1 = bf2f(acc[r1][ix]);

            const float4* wp = reinterpret_cast<const float4*>(W + f * 16);
            float4 wa = wp[0];
            float4 wb = wp[1];
            float4 wc = wp[2];
            float4 wd = wp[3];
            float w[16] = { wa.x, wa.y, wa.z, wa.w,
                            wb.x, wb.y, wb.z, wb.w,
                            wc.x, wc.y, wc.z, wc.w,
                            wd.x, wd.y, wd.z, wd.w };

            #pragma unroll
            for (int o = 0; o < 16; ++o) {
                acc0[o] = fmaf(a0, w[o], acc0[o]);
                acc1[o] = fmaf(a1, w[o], acc1[o]);
            }
        }

        // tanh + pack to bf16, write 16 cols per row (32 B, uint4-aligned)
        uint4 q0, q1;
        q0.x = pack2bf(fast_tanh(acc0[0]),  fast_tanh(acc0[1]));
        q0.y = pack2bf(fast_tanh(acc0[2]),  fast_tanh(acc0[3]));
        q0.z = pack2bf(fast_tanh(acc0[4]),  fast_tanh(acc0[5]));
        q0.w = pack2bf(fast_tanh(acc0[6]),  fast_tanh(acc0[7]));
        q1.x = pack2bf(fast_tanh(acc0[8]),  fast_tanh(acc0[9]));
        q1.y = pack2bf(fast_tanh(acc0[10]), fast_tanh(acc0[11]));
        q1.z = pack2bf(fast_tanh(acc0[12]), fast_tanh(acc0[13]));
        q1.w = pack2bf(fast_tanh(acc0[14]), fast_tanh(acc0[15]));
        uint4* d0 = reinterpret_cast<uint4*>(&acc[r0][out_base + g * 16]);
        d0[0] = q0;
        d0[1] = q1;

        q0.x = pack2bf(fast_tanh(acc1[0]),  fast_tanh(acc1[1]));
        q0.y = pack2bf(fast_tanh(acc1[2]),  fast_tanh(acc1[3]));
        q0.z = pack2bf(fast_tanh(acc1[4]),  fast_tanh(acc1[5]));
        q0.w = pack2bf(fast_tanh(acc1[6]),  fast_tanh(acc1[7]));
        q1.x = pack2bf(fast_tanh(acc1[8]),  fast_tanh(acc1[9]));
        q1.y = pack2bf(fast_tanh(acc1[10]), fast_tanh(acc1[11]));
        q1.z = pack2bf(fast_tanh(acc1[12]), fast_tanh(acc1[13]));
        q1.w = pack2bf(fast_tanh(acc1[14]), fast_tanh(acc1[15]));
        uint4* d1 = reinterpret_cast<uint4*>(&acc[r1][out_base + g * 16]);
        d1[0] = q0;
        d1[1] = q1;

        out_base += 1024;
        __syncthreads();
    }

    // ---- Head: thread owns (go=j>>4, oo=j&15) for rows {rb, rb+1} ----
    {
        const int j = t & 63;          // output col 0..63
        const int go = j >> 4;         // 0..3
        const int oo = j & 15;         // 0..15
        const int rb = (t >> 6) * 2;   // 0,2,4,6

        const int* idx = idxo + go * 48;
        const float* W = Wo + go * 768;   // go*48*16

        float sum0 = bo[go * 16 + oo];
        float sum1 = sum0;

        for (int f = 0; f < 48; ++f) {
            const int ix = idx[f];
            const float w = W[f * 16 + oo];
            sum0 = fmaf(bf2f(acc[rb][ix]), w, sum0);
            sum1 = fmaf(bf2f(acc[rb + 1][ix]), w, sum1);
        }

        out[(size_t)(row0 + rb) * 64 + j] = sum0;
        out[(size_t)(row0 + rb + 1) * 64 + j] = sum1;
    }
}

extern "C" void kernel_launch(void* const* d_in, const int* in_sizes, int n_in,
                              void* d_out, int out_size, void* d_ws, size_t ws_size,
                              hipStream_t stream) {
    const float* x  = (const float*)d_in[0];
    const float* W1 = (const float*)d_in[1];
    const float* b1 = (const float*)d_in[2];
    const float* W2 = (const float*)d_in[3];
    const float* b2 = (const float*)d_in[4];
    const float* W3 = (const float*)d_in[5];
    const float* b3 = (const float*)d_in[6];
    const float* Wo = (const float*)d_in[7];
    const float* bo = (const float*)d_in[8];
    const int* idx1 = (const int*)d_in[9];
    const int* idx2 = (const int*)d_in[10];
    const int* idx3 = (const int*)d_in[11];
    const int* idxo = (const int*)d_in[12];
    float* out = (float*)d_out;

    const int B = in_sizes[0] / 512;            // 16384
    const int grid = B / ROWS_PER_BLOCK;        // 2048

    demodel_kernel<<<grid, BLOCK_THREADS, 0, stream>>>(
        x, W1, b1, W2, b2, W3, b3, Wo, bo, idx1, idx2, idx3, idxo, out);
}